// Round 3
// baseline (367.589 us; speedup 1.0000x reference)
//
#include <hip/hip_runtime.h>
#include <math.h>

// Twist (axis-angle) -> rotation matrix, Rodrigues formula.
// Input:  [8388608, 3] f32 ; Output: [8388608, 3, 3] f32.
// Memory-bound streaming: 100.7 MB read + 302 MB write, floor ~64 us.
//
// v5: pipelined persistent waves, correctly fenced.
// v4's barrier-free LDS exchange was a cross-lane data race (compiler
// reasons per-thread; no lgkmcnt waits were inserted for other lanes'
// ds_writes) -> NaN. v5 keeps the grid-stride prefetch pipeline but:
//   - input: direct strided dwordx4 loads (lane reads v4f 3*lane+j of its
//     tile) — no input LDS phase at all, every byte still read once;
//   - output: wave-private LDS transpose guarded by WAVE-LOCAL fences
//     (s_waitcnt lgkmcnt(0) + sched_barrier, "memory" clobber). No
//     s_barrier, no vmcnt drain anywhere in the loop, so next-tile loads
//     and nontemporal stores stay in flight across iterations.
//
// LDS bank check: write 9*lane+k -> start bank (4l+4k)%32, lanes 0..7 hit
// all 32 banks once (2 lanes/bank over 64 lanes = free); readback linear.

typedef float v4f __attribute__((ext_vector_type(4)));

#define TPB 256
#define NWAVE (TPB / 64)
#define T_IN 192                  // v4f per 256-rotation tile in  (3 KB)
#define T_OUT 576                 // v4f per tile out (9 KB)
#define GRID 1024                 // 4096 waves, all resident (4 blk/CU @ 36KB)

// Wave-local LDS fence: all of THIS wave's outstanding DS ops complete;
// compiler may not move memory ops across it. Does NOT touch vmcnt, so
// global-load prefetch / nontemporal stores keep flowing.
#define WAVE_LDS_FENCE()                                      \
    do {                                                      \
        asm volatile("s_waitcnt lgkmcnt(0)" ::: "memory");    \
        __builtin_amdgcn_sched_barrier(0);                    \
    } while (0)

__global__ __launch_bounds__(TPB, 4) void twist2mat_kernel(
    const v4f* __restrict__ in4, v4f* __restrict__ out4, const int ntiles) {
    __shared__ v4f buf[NWAVE][T_OUT];          // 36 KB/block
    const int wid  = threadIdx.x >> 6;
    const int lane = threadIdx.x & 63;
    v4f* wbuf = buf[wid];
    const int nw = GRID * NWAVE;

    int tile = blockIdx.x * NWAVE + wid;
    if (tile >= ntiles) return;

    // Prologue: this lane's 4 rotations (12 floats) as 3 strided dwordx4.
    v4f x0 = in4[tile * T_IN + 3 * lane + 0];
    v4f x1 = in4[tile * T_IN + 3 * lane + 1];
    v4f x2 = in4[tile * T_IN + 3 * lane + 2];

    for (; tile < ntiles; tile += nw) {
        const float w[12] = {x0.x, x0.y, x0.z, x0.w,
                             x1.x, x1.y, x1.z, x1.w,
                             x2.x, x2.y, x2.z, x2.w};

        // Prefetch next tile NOW; waits for it are only emitted at the
        // next iteration's w[] use, so it overlaps compute + LDS + stores.
        const int nt = tile + nw;
        if (nt < ntiles) {
            x0 = in4[nt * T_IN + 3 * lane + 0];
            x1 = in4[nt * T_IN + 3 * lane + 1];
            x2 = in4[nt * T_IN + 3 * lane + 2];
        }

        float o[36];
#pragma unroll
        for (int j = 0; j < 4; ++j) {
            const float w0 = w[3 * j], w1 = w[3 * j + 1], w2 = w[3 * j + 2];
            const float n2  = fmaf(w0, w0, fmaf(w1, w1, w2 * w2));
            const float t   = fmaxf(sqrtf(n2), 1e-5f);   // clamp(||w||,1e-5)
            const float inv = 1.0f / t;
            const float a0 = w0 * inv, a1 = w1 * inv, a2 = w2 * inv;
            float s, c;
            __sincosf(t, &s, &c);
            const float c1 = 1.0f - c;
            // AA = a a^T - (a.a) I  (exact A@A for the clamped case).
            const float aa = fmaf(a0, a0, fmaf(a1, a1, a2 * a2));
            float* r = &o[9 * j];
            r[0] = fmaf(c1, fmaf(a0, a0, -aa), 1.0f);
            r[1] = fmaf(c1, a0 * a1, -s * a2);
            r[2] = fmaf(c1, a0 * a2,  s * a1);
            r[3] = fmaf(c1, a0 * a1,  s * a2);
            r[4] = fmaf(c1, fmaf(a1, a1, -aa), 1.0f);
            r[5] = fmaf(c1, a1 * a2, -s * a0);
            r[6] = fmaf(c1, a0 * a2, -s * a1);
            r[7] = fmaf(c1, a1 * a2,  s * a0);
            r[8] = fmaf(c1, fmaf(a2, a2, -aa), 1.0f);
        }

        // Previous iteration's readback reads must have completed before
        // we overwrite the wave's LDS slice (cross-lane WAR).
        WAVE_LDS_FENCE();

        // Registers -> LDS in output-linear order (9 x ds_write_b128).
#pragma unroll
        for (int k = 0; k < 9; ++k) {
            v4f v = {o[4 * k + 0], o[4 * k + 1], o[4 * k + 2], o[4 * k + 3]};
            wbuf[9 * lane + k] = v;
        }

        // Writes visible to all lanes of this wave (cross-lane RAW).
        WAVE_LDS_FENCE();

        // Readback linear + nontemporal streaming stores.
#pragma unroll
        for (int k = 0; k < 9; ++k)
            __builtin_nontemporal_store(wbuf[lane + 64 * k],
                                        &out4[tile * T_OUT + lane + 64 * k]);
    }
}

extern "C" void kernel_launch(void* const* d_in, const int* in_sizes, int n_in,
                              void* d_out, int out_size, void* d_ws, size_t ws_size,
                              hipStream_t stream) {
    (void)n_in; (void)out_size; (void)d_ws; (void)ws_size;
    const v4f* in4 = (const v4f*)d_in[0];
    v4f* out4 = (v4f*)d_out;
    const int nrot = in_sizes[0] / 3;          // 8,388,608
    const int ntiles = nrot / 256;             // 32768 tiles
    twist2mat_kernel<<<GRID, TPB, 0, stream>>>(in4, out4, ntiles);
}

// Round 4
// 358.317 us; speedup vs baseline: 1.0259x; 1.0259x over previous
//
#include <hip/hip_runtime.h>
#include <math.h>

// Twist (axis-angle) -> rotation matrix, Rodrigues formula.
// Input:  [8388608, 3] f32 ; Output: [8388608, 3, 3] f32.
// Memory-bound streaming: 100.7 MB read + 302 MB write, floor ~64 us.
//
// v6: minimum-synchronization one-shot blocks.
// History: v2b/v3 (LDS in+out, 3 block barriers + vmcnt drain) ~346-355;
// v5 (persistent prefetch, strided reads) 368 — schedule changes plateau,
// so remove ALL block-level synchronization instead:
//   - input: per-thread direct load of its own 3 floats (12 B contiguous
//     -> dwordx3, perfectly coalesced; no LDS, no barrier, no vmcnt(0));
//   - output: wave-private LDS transpose with ONE wave-local lgkmcnt(0)
//     fence (mechanism validated by v5's passing run). Zero __syncthreads.
// Scalar out-stage writes at float index 9*lane+k: 9 coprime 32 -> 2
// lanes/bank (free). Readback linear ds_read_b128; stores nontemporal
// dwordx4, per-wave contiguous 2304 B.

typedef float v4f __attribute__((ext_vector_type(4)));

#define TPB 256
#define NWAVE (TPB / 64)
#define WOUT 576                 // floats per wave output slice (64 * 9)
#define OUT_F4 (TPB * 9 / 4)     // 576 v4f per block

__global__ __launch_bounds__(TPB, 8) void twist2mat_kernel(
    const float* __restrict__ in, v4f* __restrict__ out4) {
    __shared__ float fbuf[NWAVE * WOUT];     // 9 KB -> 8 blocks/CU
    const int tid  = threadIdx.x;
    const int wid  = tid >> 6;
    const int lane = tid & 63;
    float* wbuf = fbuf + wid * WOUT;

    const int gid = blockIdx.x * TPB + tid;  // rotation index
    const float w0 = in[3 * gid + 0];
    const float w1 = in[3 * gid + 1];
    const float w2 = in[3 * gid + 2];

    const float n2  = fmaf(w0, w0, fmaf(w1, w1, w2 * w2));
    const float t   = fmaxf(sqrtf(n2), 1e-5f);   // clamp(||w||, 1e-5)
    const float inv = 1.0f / t;
    const float a0 = w0 * inv, a1 = w1 * inv, a2 = w2 * inv;
    float s, c;
    __sincosf(t, &s, &c);
    const float c1 = 1.0f - c;
    // AA = a a^T - (a.a) I  (exact A@A for the clamped non-unit case).
    const float aa = fmaf(a0, a0, fmaf(a1, a1, a2 * a2));
    float r[9];
    r[0] = fmaf(c1, fmaf(a0, a0, -aa), 1.0f);
    r[1] = fmaf(c1, a0 * a1, -s * a2);
    r[2] = fmaf(c1, a0 * a2,  s * a1);
    r[3] = fmaf(c1, a0 * a1,  s * a2);
    r[4] = fmaf(c1, fmaf(a1, a1, -aa), 1.0f);
    r[5] = fmaf(c1, a1 * a2, -s * a0);
    r[6] = fmaf(c1, a0 * a2, -s * a1);
    r[7] = fmaf(c1, a1 * a2,  s * a0);
    r[8] = fmaf(c1, fmaf(a2, a2, -aa), 1.0f);

    // Wave-private out-stage: registers -> LDS, output-linear order.
#pragma unroll
    for (int k = 0; k < 9; ++k)
        wbuf[9 * lane + k] = r[k];

    // Wave-local fence: this wave's ds_writes complete & compiler may not
    // hoist the cross-lane readback above it. No s_barrier, no vmcnt.
    asm volatile("s_waitcnt lgkmcnt(0)" ::: "memory");
    __builtin_amdgcn_sched_barrier(0);

    // Readback linear (ds_read_b128) + nontemporal contiguous stores.
    const v4f* wv = (const v4f*)wbuf;
    const int obase = blockIdx.x * OUT_F4 + wid * (WOUT / 4);  // v4f index
    __builtin_nontemporal_store(wv[lane      ], &out4[obase + lane      ]);
    __builtin_nontemporal_store(wv[lane + 64 ], &out4[obase + lane + 64 ]);
    if (lane < WOUT / 4 - 128)   // 16 lanes tail (144 v4f per wave)
        __builtin_nontemporal_store(wv[lane + 128], &out4[obase + lane + 128]);
}

extern "C" void kernel_launch(void* const* d_in, const int* in_sizes, int n_in,
                              void* d_out, int out_size, void* d_ws, size_t ws_size,
                              hipStream_t stream) {
    (void)n_in; (void)out_size; (void)d_ws; (void)ws_size;
    const float* in = (const float*)d_in[0];
    v4f* out4 = (v4f*)d_out;
    const int nrot = in_sizes[0] / 3;        // 8,388,608
    const int grid = nrot / TPB;             // exact: 32768 blocks
    twist2mat_kernel<<<grid, TPB, 0, stream>>>(in, out4);
}